// Round 7
// baseline (92.276 us; speedup 1.0000x reference)
//
#include <hip/hip_runtime.h>
#include <hip/hip_bf16.h>
#include <stdint.h>

#define Dm 128
#define BTOT (32 * 2048)
#define TILES 8

typedef short s16x8 __attribute__((ext_vector_type(8)));
typedef float f32x4 __attribute__((ext_vector_type(4)));

__device__ float g_Wq[Dm * Dm];   // Wq_c[g][d] = sum_f wq[g][f] * p_w2[f][d]
__device__ float g_Wk[Dm * Dm];
__device__ float g_bq[Dm], g_bk[Dm];
__device__ float g_u[Dm], g_w[Dm], g_c[1];
// frag buffer (shorts): [0,16384) M (32 slots), [16384,24576) W2f (16 slots), [24576,32768) W1f (16 slots)
__device__ __align__(16) unsigned short g_AllFrag[32768];

__device__ __forceinline__ float fast_sigmoid(float x) { return 1.0f / (1.0f + __expf(-x)); }
__device__ __forceinline__ float fast_tanh(float x) { return 1.0f - 2.0f / (__expf(2.0f * x) + 1.0f); }

__device__ __forceinline__ unsigned short f2bf(float f) {  // RNE f32->bf16 (precompute only)
    unsigned u = __float_as_uint(f);
    u += 0x7fffu + ((u >> 16) & 1u);
    return (unsigned short)(u >> 16);
}

__device__ __forceinline__ unsigned pk2(float lo, float hi) {  // 2×f32 -> packed 2×bf16 (RNE fptrunc)
    unsigned short ua = __builtin_bit_cast(unsigned short, (__bf16)lo);
    unsigned short ub = __builtin_bit_cast(unsigned short, (__bf16)hi);
    return (unsigned)ua | ((unsigned)ub << 16);
}

__device__ __forceinline__ s16x8 mk8(unsigned a, unsigned b, unsigned c, unsigned d) {
    union { unsigned u[4]; s16x8 v; } t;
    t.u[0] = a; t.u[1] = b; t.u[2] = c; t.u[3] = d;
    return t.v;
}

// rpf + sj for one wave's 2 positions (16 cols), k-map f(g,j)=4g+(j&3)+16*(j>>2).
__device__ __forceinline__ void compute_rpf(float xv, int g,
                                            const float* __restrict__ p_w1,
                                            const float* __restrict__ p_b1,
                                            s16x8* rpf, float& sj_out) {
    float sj = 0.f;
#pragma unroll
    for (int kc = 0; kc < 4; ++kc) {
        unsigned wds[4];
#pragma unroll
        for (int jh = 0; jh < 2; ++jh) {
            const int d4 = kc * 32 + 4 * g + 16 * jh;
            f32x4 w1v = *(const f32x4*)&p_w1[d4];
            f32x4 b1v = *(const f32x4*)&p_b1[d4];
            f32x4 wvv = *(const f32x4*)&g_w[d4];
            float v[4];
#pragma unroll
            for (int jj = 0; jj < 4; ++jj) {
                float val = fmaxf(fmaf(xv, w1v[jj], b1v[jj]), 0.f);
                sj = fmaf(wvv[jj], val, sj);
                v[jj] = val;
            }
            wds[jh * 2 + 0] = pk2(v[0], v[1]);
            wds[jh * 2 + 1] = pk2(v[2], v[3]);
        }
        rpf[kc] = mk8(wds[0], wds[1], wds[2], wds[3]);
    }
    sj += __shfl_xor(sj, 16);
    sj += __shfl_xor(sj, 32);
    sj_out = sj;
}

// blocks 0..127: combined Wq_c/Wk_c/bq/bk; 128: W1 frags (+bias col k=40); 129: W2 frags.
__global__ __launch_bounds__(128) void k_pre1(const float* __restrict__ wq,
                                              const float* __restrict__ wk,
                                              const float* __restrict__ pw2,
                                              const float* __restrict__ pb2,
                                              const float* __restrict__ ce_w1,
                                              const float* __restrict__ ce_b1,
                                              const float* __restrict__ ce_w2) {
    const int b = blockIdx.x, t = threadIdx.x;
    if (b < 128) {
        const int g = b, d = t;
        float aq = 0.f, ak = 0.f;
        for (int f = 0; f < Dm; ++f) {
            float pv = pw2[f * Dm + d];
            aq = fmaf(wq[g * Dm + f], pv, aq);
            ak = fmaf(wk[g * Dm + f], pv, ak);
        }
        g_Wq[g * Dm + d] = aq;
        g_Wk[g * Dm + d] = ak;
        if (d == 0) {
            float bq = 0.f, bk = 0.f;
            for (int f = 0; f < Dm; ++f) {
                bq = fmaf(wq[g * Dm + f], pb2[f], bq);
                bk = fmaf(wk[g * Dm + f], pb2[f], bk);
            }
            g_bq[g] = bq;
            g_bk[g] = bk;
        }
    } else if (b == 128) {
        // W1f: slot s = rt*2+kc (rt 0..7, kc 0..1); row = 16rt+(l&15); k = kc*32+4g+(j&3)+16*(j>>2)
        for (int s = t; s < 1024; s += 128) {  // s = slot*64 + l
            int l = s & 63, slot = s >> 6;
            int rt = slot >> 1, kc = slot & 1;
            int row = rt * 16 + (l & 15), gg = l >> 4;
#pragma unroll
            for (int j = 0; j < 8; ++j) {
                int k = kc * 32 + 4 * gg + (j & 3) + 16 * (j >> 2);
                float v = (k < 40) ? ce_w1[row * 40 + k] : ((k == 40) ? ce_b1[row] : 0.f);
                g_AllFrag[24576 + s * 8 + j] = f2bf(v);
            }
        }
    } else {
        // W2f: slot = rt2*4+kc (rt2 0..3, kc 0..3); o = 16rt2+(l&15)
        for (int s = t; s < 1024; s += 128) {
            int l = s & 63, slot = s >> 6;
            int rt2 = slot >> 2, kc = slot & 3;
            int o = rt2 * 16 + (l & 15), gg = l >> 4;
#pragma unroll
            for (int j = 0; j < 8; ++j) {
                int k = kc * 32 + 4 * gg + (j & 3) + 16 * (j >> 2);
                g_AllFrag[16384 + s * 8 + j] = f2bf(ce_w2[o * Dm + k]);
            }
        }
    }
}

// blocks 0..31: M bf16 A-frags (slot b = rt*4+kc); block 32: u/w/c.
__global__ __launch_bounds__(128) void k_pre2() {
    const int b = blockIdx.x, tid = threadIdx.x;
    if (b < 32) {
        const int kc = b & 3, rt = b >> 2;
        const int l = tid & 63, jh = tid >> 6;
        const int row = rt * 16 + (l & 15), g = l >> 4;
#pragma unroll
        for (int jj = 0; jj < 4; ++jj) {
            int e = kc * 32 + 4 * g + jj + 16 * jh;
            float acc = 0.f;
            for (int gg = 0; gg < Dm; ++gg)
                acc = fmaf(g_Wq[gg * Dm + row], g_Wk[gg * Dm + e], acc);
            g_AllFrag[(b * 64 + l) * 8 + 4 * jh + jj] = f2bf(acc);
        }
    } else {
        const int d = tid;
        float ua = 0.f, wa = 0.f;
        for (int g = 0; g < Dm; ++g) {
            ua = fmaf(g_Wq[g * Dm + d], g_bk[g], ua);
            wa = fmaf(g_Wk[g * Dm + d], g_bq[g], wa);
        }
        g_u[d] = ua;
        g_w[d] = wa;
        if (d == 0) {
            float c = 0.f;
            for (int g = 0; g < Dm; ++g) c = fmaf(g_bq[g], g_bk[g], c);
            g_c[0] = c;
        }
    }
}

// 512 threads = 8 waves; block handles TILES tiles of 16 positions; M staged once.
__global__ __launch_bounds__(512, 4) void k_fused(const float* __restrict__ x,
                                                  const float* __restrict__ hist,
                                                  const float* __restrict__ ce_b2,
                                                  const float* __restrict__ p_w1,
                                                  const float* __restrict__ p_b1,
                                                  float* __restrict__ pred_out,
                                                  float* __restrict__ A_out) {
    __shared__ __align__(16) unsigned short lds_m[16384];    // M frags, 32 KB (block-static)
    __shared__ __align__(16) unsigned short lds_hB[2048];    // h in gate-B-frag layout, 4 KB
    __shared__ __align__(16) float lds_hist[2][16 * 41];     // dbuf, padded stride 41
    __shared__ __align__(16) float lds_gate[16][68];         // [tile pos][o]

    const int tid = threadIdx.x;
    const int wv = tid >> 6;       // 0..7
    const int l = tid & 63;
    const int g = l >> 4, c16 = l & 15;
    const long base16 = (long)blockIdx.x * (16 * TILES);

    // ---- prologue: stage M (once), hoist W frags, hist tile 0, rpf tile 0 ----
    {
        const char* gsrc = (const char*)g_AllFrag + (size_t)wv * 4096 + (size_t)l * 16;
        char* ldst = (char*)lds_m + wv * 4096;
#pragma unroll
        for (int q = 0; q < 4; ++q)
            __builtin_amdgcn_global_load_lds(
                (const __attribute__((address_space(1))) unsigned int*)(gsrc + q * 1024),
                (__attribute__((address_space(3))) unsigned int*)(ldst + q * 1024), 16, 0, 0);
    }
    s16x8 w1fA[2];
#pragma unroll
    for (int kc = 0; kc < 2; ++kc)
        w1fA[kc] = *(const s16x8*)&g_AllFrag[24576 + ((wv * 2 + kc) * 64 + l) * 8];
    s16x8 w2fA[4];
    f32x4 b2v;
    if (wv < 4) {
#pragma unroll
        for (int kc = 0; kc < 4; ++kc)
            w2fA[kc] = *(const s16x8*)&g_AllFrag[16384 + ((wv * 4 + kc) * 64 + l) * 8];
        b2v = *(const f32x4*)&ce_b2[16 * wv + 4 * g];
    }
    const float cc = g_c[0];
    {
        const float* hsrc = hist + base16 * 40;
        float a = hsrc[tid];
        lds_hist[0][(tid / 40) * 41 + (tid % 40)] = a;
        if (tid < 128) {
            float bvv = hsrc[512 + tid];
            lds_hist[0][((512 + tid) / 40) * 41 + ((512 + tid) % 40)] = bvv;
        }
    }
    const int np = c16 >> 3, i_me = c16 & 7;
    const int myoff = wv * 2 + np;          // wave's position within tile for col c16
    float xv = x[(base16 + myoff) * 8 + i_me];
    s16x8 rpf[4];
    float sj;
    compute_rpf(xv, g, p_w1, p_b1, rpf, sj);

    __syncthreads();  // bar1: M DMA drained, hist0 visible

    for (int t = 0; t < TILES; ++t) {
        // ---- prefetch next tile's hist + x (issued early, hidden under C/D) ----
        float hr0 = 0.f, hr1 = 0.f, xvn = 0.f;
        if (t + 1 < TILES) {
            const float* hsrc = hist + (base16 + (t + 1) * 16) * 40;
            hr0 = hsrc[tid];
            if (tid < 128) hr1 = hsrc[512 + tid];
            xvn = x[(base16 + (t + 1) * 16 + myoff) * 8 + i_me];
        }

        // ---- C: hist B-frags (cols = 16 tile positions; bias-1 at k=40) ----
        const float* hl = &lds_hist[t & 1][c16 * 41];
        s16x8 histB[2];
        histB[0] = mk8(pk2(hl[4 * g + 0], hl[4 * g + 1]),
                       pk2(hl[4 * g + 2], hl[4 * g + 3]),
                       pk2(hl[16 + 4 * g + 0], hl[16 + 4 * g + 1]),
                       pk2(hl[16 + 4 * g + 2], hl[16 + 4 * g + 3]));
        {
            float v[4];
#pragma unroll
            for (int jj = 0; jj < 4; ++jj) {
                int k = 32 + 4 * g + jj;
                int kk = (k < 40) ? k : 0;
                float tt = hl[kk];
                tt = (k < 40) ? tt : 0.f;
                v[jj] = (k == 40) ? 1.f : tt;   // bias column
            }
            histB[1] = mk8(pk2(v[0], v[1]), pk2(v[2], v[3]), 0u, 0u);
        }

        // ---- D: h MFMA (row-tile rt = wv); publish relu(h) as gate-B-frag slice ----
        f32x4 hC = (f32x4){0.f, 0.f, 0.f, 0.f};
        hC = __builtin_amdgcn_mfma_f32_16x16x32_bf16(w1fA[0], histB[0], hC, 0, 0, 0);
        hC = __builtin_amdgcn_mfma_f32_16x16x32_bf16(w1fA[1], histB[1], hC, 0, 0, 0);
        {
            unsigned* dst = (unsigned*)&lds_hB[((wv >> 1) * 64 + l) * 8 + (wv & 1) * 4];
            dst[0] = pk2(fmaxf(hC[0], 0.f), fmaxf(hC[1], 0.f));
            dst[1] = pk2(fmaxf(hC[2], 0.f), fmaxf(hC[3], 0.f));
        }

        __syncthreads();  // bar2: hB visible (also drains prefetch loads)

        // ---- E: gate MFMA (waves 0..3: output row-tile rt2 = wv) ----
        if (wv < 4) {
            s16x8 gB[4];
#pragma unroll
            for (int kc = 0; kc < 4; ++kc)
                gB[kc] = *(const s16x8*)&lds_hB[(kc * 64 + l) * 8];
            f32x4 gC = b2v;
#pragma unroll
            for (int kc = 0; kc < 4; ++kc)
                gC = __builtin_amdgcn_mfma_f32_16x16x32_bf16(w2fA[kc], gB[kc], gC, 0, 0, 0);
            f32x4 sg;
#pragma unroll
            for (int jj = 0; jj < 4; ++jj) sg[jj] = fast_sigmoid(gC[jj]);
            *(f32x4*)&lds_gate[c16][16 * wv + 4 * g] = sg;
        }

        // ---- F: Y = M @ RP + u (u as C-init), yf, S = RP^T @ Y' ----
        f32x4 Yacc[8];
#pragma unroll
        for (int r = 0; r < 8; ++r) Yacc[r] = *(const f32x4*)&g_u[16 * r + 4 * g];
#pragma unroll
        for (int kc = 0; kc < 4; ++kc) {
#pragma unroll
            for (int r = 0; r < 8; ++r) {
                s16x8 af = *(const s16x8*)&lds_m[((r * 4 + kc) * 64 + l) * 8];
                Yacc[r] = __builtin_amdgcn_mfma_f32_16x16x32_bf16(af, rpf[kc], Yacc[r], 0, 0, 0);
            }
        }
        s16x8 yf[4];
#pragma unroll
        for (int kc = 0; kc < 4; ++kc)
            yf[kc] = mk8(pk2(Yacc[2 * kc][0], Yacc[2 * kc][1]),
                         pk2(Yacc[2 * kc][2], Yacc[2 * kc][3]),
                         pk2(Yacc[2 * kc + 1][0], Yacc[2 * kc + 1][1]),
                         pk2(Yacc[2 * kc + 1][2], Yacc[2 * kc + 1][3]));
        f32x4 Sacc = (f32x4){0.f, 0.f, 0.f, 0.f};
#pragma unroll
        for (int kc = 0; kc < 4; ++kc)
            Sacc = __builtin_amdgcn_mfma_f32_16x16x32_bf16(rpf[kc], yf[kc], Sacc, 0, 0, 0);

        // ---- write next tile's hist into the alternate buffer ----
        if (t + 1 < TILES) {
            lds_hist[(t + 1) & 1][(tid / 40) * 41 + (tid % 40)] = hr0;
            if (tid < 128)
                lds_hist[(t + 1) & 1][((512 + tid) / 40) * 41 + ((512 + tid) % 40)] = hr1;
        }

        __syncthreads();  // bar3: lds_gate + next hist visible

        // ---- G: epilogue for tile t ----
        const int jv = c16 & 7;
        const bool diag = ((g >> 1) == np);
        const long bt = base16 + t * 16 + wv * 2 + np;
        float Av[4], pr[4];
#pragma unroll
        for (int q = 0; q < 4; ++q) {
            float sc = (Sacc[q] + sj + cc) * 0.08838834764831845f;
            float gv = lds_gate[wv * 2 + np][(4 * (g & 1) + q) * 8 + jv];
            Av[q] = fast_tanh(sc) * gv;
            pr[q] = Av[q] * xv;
            pr[q] += __shfl_xor(pr[q], 1);
            pr[q] += __shfl_xor(pr[q], 2);
            pr[q] += __shfl_xor(pr[q], 4);
        }
        if (diag) {
            float* Ap = A_out + bt * 64 + jv;
#pragma unroll
            for (int q = 0; q < 4; ++q) Ap[((g & 1) * 4 + q) * 8] = Av[q];
            if (jv == 0) {
                float* Pp = pred_out + bt * 8 + (g & 1) * 4;
#pragma unroll
                for (int q = 0; q < 4; ++q) Pp[q] = pr[q];
            }
        }

        // ---- B(t+1): rpf for next tile (xv consumed above, safe to overwrite) ----
        if (t + 1 < TILES) {
            xv = xvn;
            compute_rpf(xv, g, p_w1, p_b1, rpf, sj);
        }
    }
}

extern "C" void kernel_launch(void* const* d_in, const int* in_sizes, int n_in,
                              void* d_out, int out_size, void* d_ws, size_t ws_size,
                              hipStream_t stream) {
    const float* x = (const float*)d_in[0];
    const float* hist = (const float*)d_in[1];
    const float* ce_w1 = (const float*)d_in[2];
    const float* ce_b1 = (const float*)d_in[3];
    const float* ce_w2 = (const float*)d_in[4];
    const float* ce_b2 = (const float*)d_in[5];
    const float* p_w1 = (const float*)d_in[6];
    const float* p_b1 = (const float*)d_in[7];
    const float* p_w2 = (const float*)d_in[8];
    const float* p_b2 = (const float*)d_in[9];
    const float* wq = (const float*)d_in[10];
    const float* wk = (const float*)d_in[11];

    float* pred_out = (float*)d_out;
    float* A_out = pred_out + (size_t)BTOT * 8;

    k_pre1<<<130, 128, 0, stream>>>(wq, wk, p_w2, p_b2, ce_w1, ce_b1, ce_w2);
    k_pre2<<<33, 128, 0, stream>>>();
    k_fused<<<BTOT / (16 * TILES), 512, 0, stream>>>(x, hist, ce_b2, p_w1, p_b1,
                                                     pred_out, A_out);
}

// Round 8
// 91.317 us; speedup vs baseline: 1.0105x; 1.0105x over previous
//
#include <hip/hip_runtime.h>
#include <hip/hip_bf16.h>
#include <stdint.h>

#define Dm 128
#define BTOT (32 * 2048)

typedef short s16x8 __attribute__((ext_vector_type(8)));
typedef float f32x4 __attribute__((ext_vector_type(4)));

__device__ float g_Wq[Dm * Dm];   // Wq_c[g][d] = sum_f wq[g][f] * p_w2[f][d]
__device__ float g_Wk[Dm * Dm];
__device__ float g_bq[Dm], g_bk[Dm];
__device__ float g_u[Dm], g_w[Dm], g_c[1];
// frag buffer (shorts): [0,16384) M (32 slots), [16384,24576) W2f (16 slots), [24576,32768) W1f (16 slots)
__device__ __align__(16) unsigned short g_AllFrag[32768];
__device__ __align__(16) float g_gate[(size_t)BTOT * 64];   // 16.7 MB staging for gate

__device__ __forceinline__ float fast_sigmoid(float x) { return 1.0f / (1.0f + __expf(-x)); }
__device__ __forceinline__ float fast_tanh(float x) { return 1.0f - 2.0f / (__expf(2.0f * x) + 1.0f); }

__device__ __forceinline__ unsigned short f2bf(float f) {  // RNE f32->bf16 (precompute only)
    unsigned u = __float_as_uint(f);
    u += 0x7fffu + ((u >> 16) & 1u);
    return (unsigned short)(u >> 16);
}

__device__ __forceinline__ unsigned pk2(float lo, float hi) {  // 2×f32 -> packed 2×bf16 (RNE fptrunc)
    unsigned short ua = __builtin_bit_cast(unsigned short, (__bf16)lo);
    unsigned short ub = __builtin_bit_cast(unsigned short, (__bf16)hi);
    return (unsigned)ua | ((unsigned)ub << 16);
}

__device__ __forceinline__ s16x8 mk8(unsigned a, unsigned b, unsigned c, unsigned d) {
    union { unsigned u[4]; s16x8 v; } t;
    t.u[0] = a; t.u[1] = b; t.u[2] = c; t.u[3] = d;
    return t.v;
}

// rpf + sj for one wave's 2 positions (16 cols), k-map f(g,j)=4g+(j&3)+16*(j>>2).
__device__ __forceinline__ void compute_rpf(float xv, int g,
                                            const float* __restrict__ p_w1,
                                            const float* __restrict__ p_b1,
                                            s16x8* rpf, float& sj_out) {
    float sj = 0.f;
#pragma unroll
    for (int kc = 0; kc < 4; ++kc) {
        unsigned wds[4];
#pragma unroll
        for (int jh = 0; jh < 2; ++jh) {
            const int d4 = kc * 32 + 4 * g + 16 * jh;
            f32x4 w1v = *(const f32x4*)&p_w1[d4];
            f32x4 b1v = *(const f32x4*)&p_b1[d4];
            f32x4 wvv = *(const f32x4*)&g_w[d4];
            float v[4];
#pragma unroll
            for (int jj = 0; jj < 4; ++jj) {
                float val = fmaxf(fmaf(xv, w1v[jj], b1v[jj]), 0.f);
                sj = fmaf(wvv[jj], val, sj);
                v[jj] = val;
            }
            wds[jh * 2 + 0] = pk2(v[0], v[1]);
            wds[jh * 2 + 1] = pk2(v[2], v[3]);
        }
        rpf[kc] = mk8(wds[0], wds[1], wds[2], wds[3]);
    }
    sj += __shfl_xor(sj, 16);
    sj += __shfl_xor(sj, 32);
    sj_out = sj;
}

// blocks 0..127: combined Wq_c/Wk_c/bq/bk; 128: W1 frags (+bias col k=40); 129: W2 frags.
__global__ __launch_bounds__(128) void k_pre1(const float* __restrict__ wq,
                                              const float* __restrict__ wk,
                                              const float* __restrict__ pw2,
                                              const float* __restrict__ pb2,
                                              const float* __restrict__ ce_w1,
                                              const float* __restrict__ ce_b1,
                                              const float* __restrict__ ce_w2) {
    const int b = blockIdx.x, t = threadIdx.x;
    if (b < 128) {
        const int g = b, d = t;
        float aq = 0.f, ak = 0.f;
        for (int f = 0; f < Dm; ++f) {
            float pv = pw2[f * Dm + d];
            aq = fmaf(wq[g * Dm + f], pv, aq);
            ak = fmaf(wk[g * Dm + f], pv, ak);
        }
        g_Wq[g * Dm + d] = aq;
        g_Wk[g * Dm + d] = ak;
        if (d == 0) {
            float bq = 0.f, bk = 0.f;
            for (int f = 0; f < Dm; ++f) {
                bq = fmaf(wq[g * Dm + f], pb2[f], bq);
                bk = fmaf(wk[g * Dm + f], pb2[f], bk);
            }
            g_bq[g] = bq;
            g_bk[g] = bk;
        }
    } else if (b == 128) {
        // W1f: slot s = rt*2+kc (rt 0..7, kc 0..1); row = 16rt+(l&15); k = kc*32+4g+(j&3)+16*(j>>2)
        for (int s = t; s < 1024; s += 128) {  // s = slot*64 + l
            int l = s & 63, slot = s >> 6;
            int rt = slot >> 1, kc = slot & 1;
            int row = rt * 16 + (l & 15), gg = l >> 4;
#pragma unroll
            for (int j = 0; j < 8; ++j) {
                int k = kc * 32 + 4 * gg + (j & 3) + 16 * (j >> 2);
                float v = (k < 40) ? ce_w1[row * 40 + k] : ((k == 40) ? ce_b1[row] : 0.f);
                g_AllFrag[24576 + s * 8 + j] = f2bf(v);
            }
        }
    } else {
        // W2f: slot = rt2*4+kc (rt2 0..3, kc 0..3); o = 16rt2+(l&15)
        for (int s = t; s < 1024; s += 128) {
            int l = s & 63, slot = s >> 6;
            int rt2 = slot >> 2, kc = slot & 3;
            int o = rt2 * 16 + (l & 15), gg = l >> 4;
#pragma unroll
            for (int j = 0; j < 8; ++j) {
                int k = kc * 32 + 4 * gg + (j & 3) + 16 * (j >> 2);
                g_AllFrag[16384 + s * 8 + j] = f2bf(ce_w2[o * Dm + k]);
            }
        }
    }
}

// blocks 0..31: M bf16 A-frags (slot b = rt*4+kc); block 32: u/w/c.
__global__ __launch_bounds__(128) void k_pre2() {
    const int b = blockIdx.x, tid = threadIdx.x;
    if (b < 32) {
        const int kc = b & 3, rt = b >> 2;
        const int l = tid & 63, jh = tid >> 6;
        const int row = rt * 16 + (l & 15), g = l >> 4;
#pragma unroll
        for (int jj = 0; jj < 4; ++jj) {
            int e = kc * 32 + 4 * g + jj + 16 * jh;
            float acc = 0.f;
            for (int gg = 0; gg < Dm; ++gg)
                acc = fmaf(g_Wq[gg * Dm + row], g_Wk[gg * Dm + e], acc);
            g_AllFrag[(b * 64 + l) * 8 + 4 * jh + jj] = f2bf(acc);
        }
    } else {
        const int d = tid;
        float ua = 0.f, wa = 0.f;
        for (int g = 0; g < Dm; ++g) {
            ua = fmaf(g_Wq[g * Dm + d], g_bk[g], ua);
            wa = fmaf(g_Wk[g * Dm + d], g_bq[g], wa);
        }
        g_u[d] = ua;
        g_w[d] = wa;
        if (d == 0) {
            float c = 0.f;
            for (int g = 0; g < Dm; ++g) c = fmaf(g_bq[g], g_bk[g], c);
            g_c[0] = c;
        }
    }
}

// Gate kernel: 256 thr = 4 waves; 16 positions/block. h MFMA (wave wv: row-tiles
// 2wv,2wv+1) -> hB exchange -> gate MFMA (wave wv: o-rows 16wv..16wv+15) -> g_gate.
__global__ __launch_bounds__(256) void k_gate(const float* __restrict__ hist,
                                              const float* __restrict__ ce_b2) {
    __shared__ __align__(16) unsigned short lds_hB[2048];  // 4 KB
    __shared__ __align__(16) float lds_hist[16 * 41];      // padded stride 41

    const int tid = threadIdx.x;
    const int wv = tid >> 6;       // 0..3
    const int l = tid & 63;
    const int g = l >> 4, c16 = l & 15;
    const long base16 = (long)blockIdx.x * 16;

    // stage hist (640 floats)
    {
        const float* hsrc = hist + base16 * 40;
        lds_hist[(tid / 40) * 41 + (tid % 40)] = hsrc[tid];
        int i2 = tid + 256;
        lds_hist[(i2 / 40) * 41 + (i2 % 40)] = hsrc[i2];
        if (tid < 128) {
            int i3 = tid + 512;
            lds_hist[(i3 / 40) * 41 + (i3 % 40)] = hsrc[i3];
        }
    }
    // W frags to regs
    s16x8 w1fA[2][2];
#pragma unroll
    for (int rr = 0; rr < 2; ++rr)
#pragma unroll
        for (int kc = 0; kc < 2; ++kc)
            w1fA[rr][kc] = *(const s16x8*)&g_AllFrag[24576 + (((2 * wv + rr) * 2 + kc) * 64 + l) * 8];
    s16x8 w2fA[4];
#pragma unroll
    for (int kc = 0; kc < 4; ++kc)
        w2fA[kc] = *(const s16x8*)&g_AllFrag[16384 + ((wv * 4 + kc) * 64 + l) * 8];
    f32x4 b2v = *(const f32x4*)&ce_b2[16 * wv + 4 * g];

    __syncthreads();  // hist visible

    // hist B-frags (cols = 16 positions; bias-1 at k=40)
    const float* hl = lds_hist + c16 * 41;
    s16x8 histB[2];
    histB[0] = mk8(pk2(hl[4 * g + 0], hl[4 * g + 1]),
                   pk2(hl[4 * g + 2], hl[4 * g + 3]),
                   pk2(hl[16 + 4 * g + 0], hl[16 + 4 * g + 1]),
                   pk2(hl[16 + 4 * g + 2], hl[16 + 4 * g + 3]));
    {
        float v[4];
#pragma unroll
        for (int jj = 0; jj < 4; ++jj) {
            int k = 32 + 4 * g + jj;
            int kk = (k < 40) ? k : 0;
            float t = hl[kk];
            t = (k < 40) ? t : 0.f;
            v[jj] = (k == 40) ? 1.f : t;       // bias column
        }
        histB[1] = mk8(pk2(v[0], v[1]), pk2(v[2], v[3]), 0u, 0u);
    }

    // h MFMA: row-tiles rt = 2wv+rr; publish relu(h) in gate-B-frag layout
#pragma unroll
    for (int rr = 0; rr < 2; ++rr) {
        f32x4 hC = (f32x4){0.f, 0.f, 0.f, 0.f};
        hC = __builtin_amdgcn_mfma_f32_16x16x32_bf16(w1fA[rr][0], histB[0], hC, 0, 0, 0);
        hC = __builtin_amdgcn_mfma_f32_16x16x32_bf16(w1fA[rr][1], histB[1], hC, 0, 0, 0);
        unsigned* dst = (unsigned*)&lds_hB[(wv * 64 + l) * 8 + rr * 4];
        dst[0] = pk2(fmaxf(hC[0], 0.f), fmaxf(hC[1], 0.f));
        dst[1] = pk2(fmaxf(hC[2], 0.f), fmaxf(hC[3], 0.f));
    }

    __syncthreads();  // hB visible

    // gate MFMA: wave wv owns o-rows 16wv..16wv+15; write f32 gate to global
    s16x8 gB[4];
#pragma unroll
    for (int kc = 0; kc < 4; ++kc)
        gB[kc] = *(const s16x8*)&lds_hB[(kc * 64 + l) * 8];
    f32x4 gC = b2v;
#pragma unroll
    for (int kc = 0; kc < 4; ++kc)
        gC = __builtin_amdgcn_mfma_f32_16x16x32_bf16(w2fA[kc], gB[kc], gC, 0, 0, 0);
    f32x4 sg;
#pragma unroll
    for (int jj = 0; jj < 4; ++jj) sg[jj] = fast_sigmoid(gC[jj]);
    *(f32x4*)&g_gate[(base16 + c16) * 64 + 16 * wv + 4 * g] = sg;
}

// Main kernel: 256 thr = 4 waves; 8 positions/block; ONE barrier (M staging),
// then every wave independent: rpf -> Y(32 MFMA) -> S(4 MFMA) -> epilogue.
__global__ __launch_bounds__(256) void k_main(const float* __restrict__ x,
                                              const float* __restrict__ p_w1,
                                              const float* __restrict__ p_b1,
                                              float* __restrict__ pred_out,
                                              float* __restrict__ A_out) {
    __shared__ __align__(16) unsigned short lds_m[16384];  // M frags, 32 KB exactly

    const int tid = threadIdx.x;
    const int wv = tid >> 6;       // 0..3
    const int l = tid & 63;
    const int g = l >> 4, c16 = l & 15;
    const long bt0 = (long)blockIdx.x * 8 + wv * 2;

    // stage M frags via DMA: 4 waves x 8 KB
    {
        const char* gsrc = (const char*)g_AllFrag + (size_t)wv * 8192 + (size_t)l * 16;
        char* ldst = (char*)lds_m + wv * 8192;
#pragma unroll
        for (int q = 0; q < 8; ++q)
            __builtin_amdgcn_global_load_lds(
                (const __attribute__((address_space(1))) unsigned int*)(gsrc + q * 1024),
                (__attribute__((address_space(3))) unsigned int*)(ldst + q * 1024), 16, 0, 0);
    }

    // rpf + gate prefetch (independent of LDS; hides DMA latency)
    const int np = c16 >> 3, i_me = c16 & 7;
    const float xv = x[(bt0 + np) * 8 + i_me];
    s16x8 rpf[4];
    float sj;
    compute_rpf(xv, g, p_w1, p_b1, rpf, sj);
    const int jv = c16 & 7;
    float gv[4];
#pragma unroll
    for (int q = 0; q < 4; ++q)
        gv[q] = g_gate[(bt0 + np) * 64 + (4 * (g & 1) + q) * 8 + jv];
    const float cc = g_c[0];

    __syncthreads();  // bar: M staged (vmcnt drained) + visible

    // Y = M @ RP + u (u as C-init)
    f32x4 Yacc[8];
#pragma unroll
    for (int r = 0; r < 8; ++r) Yacc[r] = *(const f32x4*)&g_u[16 * r + 4 * g];
#pragma unroll
    for (int kc = 0; kc < 4; ++kc) {
#pragma unroll
        for (int r = 0; r < 8; ++r) {
            s16x8 af = *(const s16x8*)&lds_m[((r * 4 + kc) * 64 + l) * 8];
            Yacc[r] = __builtin_amdgcn_mfma_f32_16x16x32_bf16(af, rpf[kc], Yacc[r], 0, 0, 0);
        }
    }
    s16x8 yf[4];
#pragma unroll
    for (int kc = 0; kc < 4; ++kc)
        yf[kc] = mk8(pk2(Yacc[2 * kc][0], Yacc[2 * kc][1]),
                     pk2(Yacc[2 * kc][2], Yacc[2 * kc][3]),
                     pk2(Yacc[2 * kc + 1][0], Yacc[2 * kc + 1][1]),
                     pk2(Yacc[2 * kc + 1][2], Yacc[2 * kc + 1][3]));
    f32x4 Sacc = (f32x4){0.f, 0.f, 0.f, 0.f};
#pragma unroll
    for (int kc = 0; kc < 4; ++kc)
        Sacc = __builtin_amdgcn_mfma_f32_16x16x32_bf16(rpf[kc], yf[kc], Sacc, 0, 0, 0);

    // epilogue
    const bool diag = ((g >> 1) == np);
    float Av[4], pr[4];
#pragma unroll
    for (int q = 0; q < 4; ++q) {
        float sc = (Sacc[q] + sj + cc) * 0.08838834764831845f;
        Av[q] = fast_tanh(sc) * gv[q];
        pr[q] = Av[q] * xv;
        pr[q] += __shfl_xor(pr[q], 1);
        pr[q] += __shfl_xor(pr[q], 2);
        pr[q] += __shfl_xor(pr[q], 4);
    }
    if (diag) {
        float* Ap = A_out + (bt0 + np) * 64 + jv;
#pragma unroll
        for (int q = 0; q < 4; ++q) Ap[((g & 1) * 4 + q) * 8] = Av[q];
        if (jv == 0) {
            float* Pp = pred_out + (bt0 + np) * 8 + (g & 1) * 4;
#pragma unroll
            for (int q = 0; q < 4; ++q) Pp[q] = pr[q];
        }
    }
}

extern "C" void kernel_launch(void* const* d_in, const int* in_sizes, int n_in,
                              void* d_out, int out_size, void* d_ws, size_t ws_size,
                              hipStream_t stream) {
    const float* x = (const float*)d_in[0];
    const float* hist = (const float*)d_in[1];
    const float* ce_w1 = (const float*)d_in[2];
    const float* ce_b1 = (const float*)d_in[3];
    const float* ce_w2 = (const float*)d_in[4];
    const float* ce_b2 = (const float*)d_in[5];
    const float* p_w1 = (const float*)d_in[6];
    const float* p_b1 = (const float*)d_in[7];
    const float* p_w2 = (const float*)d_in[8];
    const float* p_b2 = (const float*)d_in[9];
    const float* wq = (const float*)d_in[10];
    const float* wk = (const float*)d_in[11];

    float* pred_out = (float*)d_out;
    float* A_out = pred_out + (size_t)BTOT * 8;

    k_pre1<<<130, 128, 0, stream>>>(wq, wk, p_w2, p_b2, ce_w1, ce_b1, ce_w2);
    k_pre2<<<33, 128, 0, stream>>>();
    k_gate<<<BTOT / 16, 256, 0, stream>>>(hist, ce_b2);
    k_main<<<BTOT / 8, 256, 0, stream>>>(x, p_w1, p_b1, pred_out, A_out);
}

// Round 9
// 77.662 us; speedup vs baseline: 1.1882x; 1.1758x over previous
//
#include <hip/hip_runtime.h>
#include <hip/hip_bf16.h>
#include <stdint.h>

#define Dm 128
#define BTOT (32 * 2048)

typedef short s16x8 __attribute__((ext_vector_type(8)));
typedef float f32x4 __attribute__((ext_vector_type(4)));

__device__ float g_Wq[Dm * Dm];   // Wq_c[g][d] = sum_f wq[g][f] * p_w2[f][d]
__device__ float g_Wk[Dm * Dm];
__device__ float g_bq[Dm], g_bk[Dm];
__device__ float g_u[Dm], g_w[Dm], g_c[1];
// frag buffer (shorts): [0,16384) M (32 slots), [16384,24576) W2f (16 slots), [24576,32768) W1f (16 slots)
__device__ __align__(16) unsigned short g_AllFrag[32768];

__device__ __forceinline__ float fast_sigmoid(float x) { return 1.0f / (1.0f + __expf(-x)); }
__device__ __forceinline__ float fast_tanh(float x) { return 1.0f - 2.0f / (__expf(2.0f * x) + 1.0f); }

__device__ __forceinline__ unsigned short f2bf(float f) {  // RNE f32->bf16 (precompute only)
    unsigned u = __float_as_uint(f);
    u += 0x7fffu + ((u >> 16) & 1u);
    return (unsigned short)(u >> 16);
}

__device__ __forceinline__ unsigned pk2(float lo, float hi) {  // 2×f32 -> packed 2×bf16 (RNE fptrunc)
    unsigned short ua = __builtin_bit_cast(unsigned short, (__bf16)lo);
    unsigned short ub = __builtin_bit_cast(unsigned short, (__bf16)hi);
    return (unsigned)ua | ((unsigned)ub << 16);
}

__device__ __forceinline__ s16x8 mk8(unsigned a, unsigned b, unsigned c, unsigned d) {
    union { unsigned u[4]; s16x8 v; } t;
    t.u[0] = a; t.u[1] = b; t.u[2] = c; t.u[3] = d;
    return t.v;
}

// rpf + sj for one wave's 2 positions (16 cols), k-map f(g,j)=4g+(j&3)+16*(j>>2).
__device__ __forceinline__ void compute_rpf(float xv, int g,
                                            const float* __restrict__ p_w1,
                                            const float* __restrict__ p_b1,
                                            s16x8* rpf, float& sj_out) {
    float sj = 0.f;
#pragma unroll
    for (int kc = 0; kc < 4; ++kc) {
        unsigned wds[4];
#pragma unroll
        for (int jh = 0; jh < 2; ++jh) {
            const int d4 = kc * 32 + 4 * g + 16 * jh;
            f32x4 w1v = *(const f32x4*)&p_w1[d4];
            f32x4 b1v = *(const f32x4*)&p_b1[d4];
            f32x4 wvv = *(const f32x4*)&g_w[d4];
            float v[4];
#pragma unroll
            for (int jj = 0; jj < 4; ++jj) {
                float val = fmaxf(fmaf(xv, w1v[jj], b1v[jj]), 0.f);
                sj = fmaf(wvv[jj], val, sj);
                v[jj] = val;
            }
            wds[jh * 2 + 0] = pk2(v[0], v[1]);
            wds[jh * 2 + 1] = pk2(v[2], v[3]);
        }
        rpf[kc] = mk8(wds[0], wds[1], wds[2], wds[3]);
    }
    sj += __shfl_xor(sj, 16);
    sj += __shfl_xor(sj, 32);
    sj_out = sj;
}

// blocks 0..127: combined Wq_c/Wk_c/bq/bk; 128: W1 frags (+bias col k=40); 129: W2 frags.
__global__ __launch_bounds__(128) void k_pre1(const float* __restrict__ wq,
                                              const float* __restrict__ wk,
                                              const float* __restrict__ pw2,
                                              const float* __restrict__ pb2,
                                              const float* __restrict__ ce_w1,
                                              const float* __restrict__ ce_b1,
                                              const float* __restrict__ ce_w2) {
    const int b = blockIdx.x, t = threadIdx.x;
    if (b < 128) {
        const int g = b, d = t;
        float aq = 0.f, ak = 0.f;
        for (int f = 0; f < Dm; ++f) {
            float pv = pw2[f * Dm + d];
            aq = fmaf(wq[g * Dm + f], pv, aq);
            ak = fmaf(wk[g * Dm + f], pv, ak);
        }
        g_Wq[g * Dm + d] = aq;
        g_Wk[g * Dm + d] = ak;
        if (d == 0) {
            float bq = 0.f, bk = 0.f;
            for (int f = 0; f < Dm; ++f) {
                bq = fmaf(wq[g * Dm + f], pb2[f], bq);
                bk = fmaf(wk[g * Dm + f], pb2[f], bk);
            }
            g_bq[g] = bq;
            g_bk[g] = bk;
        }
    } else if (b == 128) {
        // W1f: slot s = rt*2+kc (rt 0..7, kc 0..1); row = 16rt+(l&15); k = kc*32+4g+(j&3)+16*(j>>2)
        for (int s = t; s < 1024; s += 128) {  // s = slot*64 + l
            int l = s & 63, slot = s >> 6;
            int rt = slot >> 1, kc = slot & 1;
            int row = rt * 16 + (l & 15), gg = l >> 4;
#pragma unroll
            for (int j = 0; j < 8; ++j) {
                int k = kc * 32 + 4 * gg + (j & 3) + 16 * (j >> 2);
                float v = (k < 40) ? ce_w1[row * 40 + k] : ((k == 40) ? ce_b1[row] : 0.f);
                g_AllFrag[24576 + s * 8 + j] = f2bf(v);
            }
        }
    } else {
        // W2f: slot = rt2*4+kc (rt2 0..3, kc 0..3); o = 16rt2+(l&15)
        for (int s = t; s < 1024; s += 128) {
            int l = s & 63, slot = s >> 6;
            int rt2 = slot >> 2, kc = slot & 3;
            int o = rt2 * 16 + (l & 15), gg = l >> 4;
#pragma unroll
            for (int j = 0; j < 8; ++j) {
                int k = kc * 32 + 4 * gg + (j & 3) + 16 * (j >> 2);
                g_AllFrag[16384 + s * 8 + j] = f2bf(ce_w2[o * Dm + k]);
            }
        }
    }
}

// blocks 0..31: M bf16 A-frags (slot b = rt*4+kc); block 32: u/w/c.
__global__ __launch_bounds__(128) void k_pre2() {
    const int b = blockIdx.x, tid = threadIdx.x;
    if (b < 32) {
        const int kc = b & 3, rt = b >> 2;
        const int l = tid & 63, jh = tid >> 6;
        const int row = rt * 16 + (l & 15), g = l >> 4;
#pragma unroll
        for (int jj = 0; jj < 4; ++jj) {
            int e = kc * 32 + 4 * g + jj + 16 * jh;
            float acc = 0.f;
            for (int gg = 0; gg < Dm; ++gg)
                acc = fmaf(g_Wq[gg * Dm + row], g_Wk[gg * Dm + e], acc);
            g_AllFrag[(b * 64 + l) * 8 + 4 * jh + jj] = f2bf(acc);
        }
    } else {
        const int d = tid;
        float ua = 0.f, wa = 0.f;
        for (int g = 0; g < Dm; ++g) {
            ua = fmaf(g_Wq[g * Dm + d], g_bk[g], ua);
            wa = fmaf(g_Wk[g * Dm + d], g_bq[g], wa);
        }
        g_u[d] = ua;
        g_w[d] = wa;
        if (d == 0) {
            float c = 0.f;
            for (int g = 0; g < Dm; ++g) c = fmaf(g_bq[g], g_bk[g], c);
            g_c[0] = c;
        }
    }
}

// Fused kernel: 256 thr = 4 waves; 16 positions/block; each wave owns 4 positions
// (2 rpf column-sets) so each M A-frag LDS read feeds 2 MFMAs.
__global__ __launch_bounds__(256) void k_fused(const float* __restrict__ x,
                                               const float* __restrict__ hist,
                                               const float* __restrict__ ce_b2,
                                               const float* __restrict__ p_w1,
                                               const float* __restrict__ p_b1,
                                               float* __restrict__ pred_out,
                                               float* __restrict__ A_out) {
    __shared__ __align__(16) unsigned short lds_m[16384];  // M frags, 32 KB
    __shared__ __align__(16) unsigned short lds_hB[2048];  // h in gate-B-frag layout, 4 KB
    __shared__ __align__(16) float lds_hist[16 * 41];      // padded stride 41
    __shared__ __align__(16) float lds_gate[16][68];       // [block pos][o]

    const int tid = threadIdx.x;
    const int wv = tid >> 6;       // 0..3
    const int l = tid & 63;
    const int g = l >> 4, c16 = l & 15;
    const long base = (long)blockIdx.x * 16;

    // ---- stage M frags via DMA: 4 waves x 8 KB ----
    {
        const char* gsrc = (const char*)g_AllFrag + (size_t)wv * 8192 + (size_t)l * 16;
        char* ldst = (char*)lds_m + wv * 8192;
#pragma unroll
        for (int q = 0; q < 8; ++q)
            __builtin_amdgcn_global_load_lds(
                (const __attribute__((address_space(1))) unsigned int*)(gsrc + q * 1024),
                (__attribute__((address_space(3))) unsigned int*)(ldst + q * 1024), 16, 0, 0);
    }
    // ---- stage hist (640 floats) ----
    {
        const float* hsrc = hist + base * 40;
        lds_hist[(tid / 40) * 41 + (tid % 40)] = hsrc[tid];
        int i2 = tid + 256;
        lds_hist[(i2 / 40) * 41 + (i2 % 40)] = hsrc[i2];
        if (tid < 128) {
            int i3 = tid + 512;
            lds_hist[(i3 / 40) * 41 + (i3 % 40)] = hsrc[i3];
        }
    }
    // ---- W frags to regs (dead after gate phase) ----
    s16x8 w1fA[2][2];
#pragma unroll
    for (int rr = 0; rr < 2; ++rr)
#pragma unroll
        for (int kc = 0; kc < 2; ++kc)
            w1fA[rr][kc] = *(const s16x8*)&g_AllFrag[24576 + (((2 * wv + rr) * 2 + kc) * 64 + l) * 8];
    s16x8 w2fA[4];
#pragma unroll
    for (int kc = 0; kc < 4; ++kc)
        w2fA[kc] = *(const s16x8*)&g_AllFrag[16384 + ((wv * 4 + kc) * 64 + l) * 8];
    f32x4 b2v = *(const f32x4*)&ce_b2[16 * wv + 4 * g];

    // ---- rpf for both column-sets (positions wv*4 + s*2 + np) ----
    const int np = c16 >> 3, i_me = c16 & 7;
    const float xv0 = x[(base + wv * 4 + 0 + np) * 8 + i_me];
    const float xv1 = x[(base + wv * 4 + 2 + np) * 8 + i_me];
    s16x8 rpf0[4], rpf1[4];
    float sj0, sj1;
    compute_rpf(xv0, g, p_w1, p_b1, rpf0, sj0);
    compute_rpf(xv1, g, p_w1, p_b1, rpf1, sj1);
    const float cc = g_c[0];

    __syncthreads();  // bar1: M DMA drained, hist visible

    // ---- hist B-frags (cols = 16 block positions; bias-1 at k=40) ----
    const float* hl = lds_hist + c16 * 41;
    s16x8 histB[2];
    histB[0] = mk8(pk2(hl[4 * g + 0], hl[4 * g + 1]),
                   pk2(hl[4 * g + 2], hl[4 * g + 3]),
                   pk2(hl[16 + 4 * g + 0], hl[16 + 4 * g + 1]),
                   pk2(hl[16 + 4 * g + 2], hl[16 + 4 * g + 3]));
    {
        float v[4];
#pragma unroll
        for (int jj = 0; jj < 4; ++jj) {
            int k = 32 + 4 * g + jj;
            int kk = (k < 40) ? k : 0;
            float t = hl[kk];
            t = (k < 40) ? t : 0.f;
            v[jj] = (k == 40) ? 1.f : t;       // bias column
        }
        histB[1] = mk8(pk2(v[0], v[1]), pk2(v[2], v[3]), 0u, 0u);
    }

    // ---- h MFMA: row-tiles rt = 2wv+rr; publish relu(h) in gate-B-frag layout ----
#pragma unroll
    for (int rr = 0; rr < 2; ++rr) {
        f32x4 hC = (f32x4){0.f, 0.f, 0.f, 0.f};
        hC = __builtin_amdgcn_mfma_f32_16x16x32_bf16(w1fA[rr][0], histB[0], hC, 0, 0, 0);
        hC = __builtin_amdgcn_mfma_f32_16x16x32_bf16(w1fA[rr][1], histB[1], hC, 0, 0, 0);
        unsigned* dst = (unsigned*)&lds_hB[(wv * 64 + l) * 8 + rr * 4];
        dst[0] = pk2(fmaxf(hC[0], 0.f), fmaxf(hC[1], 0.f));
        dst[1] = pk2(fmaxf(hC[2], 0.f), fmaxf(hC[3], 0.f));
    }

    __syncthreads();  // bar2: hB visible

    // ---- gate MFMA: wave wv owns o-rows 16wv..16wv+15 -> lds_gate ----
    {
        s16x8 gB[4];
#pragma unroll
        for (int kc = 0; kc < 4; ++kc)
            gB[kc] = *(const s16x8*)&lds_hB[(kc * 64 + l) * 8];
        f32x4 gC = b2v;
#pragma unroll
        for (int kc = 0; kc < 4; ++kc)
            gC = __builtin_amdgcn_mfma_f32_16x16x32_bf16(w2fA[kc], gB[kc], gC, 0, 0, 0);
        f32x4 sg;
#pragma unroll
        for (int jj = 0; jj < 4; ++jj) sg[jj] = fast_sigmoid(gC[jj]);
        *(f32x4*)&lds_gate[c16][16 * wv + 4 * g] = sg;
    }

    // ---- Y = M @ RP + u for BOTH column-sets: 32 ds_read, 64 MFMA ----
    f32x4 Yacc0[8], Yacc1[8];
#pragma unroll
    for (int r = 0; r < 8; ++r) {
        f32x4 uv = *(const f32x4*)&g_u[16 * r + 4 * g];
        Yacc0[r] = uv;
        Yacc1[r] = uv;
    }
#pragma unroll
    for (int kc = 0; kc < 4; ++kc) {
#pragma unroll
        for (int r = 0; r < 8; ++r) {
            s16x8 af = *(const s16x8*)&lds_m[((r * 4 + kc) * 64 + l) * 8];
            Yacc0[r] = __builtin_amdgcn_mfma_f32_16x16x32_bf16(af, rpf0[kc], Yacc0[r], 0, 0, 0);
            Yacc1[r] = __builtin_amdgcn_mfma_f32_16x16x32_bf16(af, rpf1[kc], Yacc1[r], 0, 0, 0);
        }
    }
    s16x8 yf0[4], yf1[4];
#pragma unroll
    for (int kc = 0; kc < 4; ++kc) {
        yf0[kc] = mk8(pk2(Yacc0[2 * kc][0], Yacc0[2 * kc][1]),
                      pk2(Yacc0[2 * kc][2], Yacc0[2 * kc][3]),
                      pk2(Yacc0[2 * kc + 1][0], Yacc0[2 * kc + 1][1]),
                      pk2(Yacc0[2 * kc + 1][2], Yacc0[2 * kc + 1][3]));
        yf1[kc] = mk8(pk2(Yacc1[2 * kc][0], Yacc1[2 * kc][1]),
                      pk2(Yacc1[2 * kc][2], Yacc1[2 * kc][3]),
                      pk2(Yacc1[2 * kc + 1][0], Yacc1[2 * kc + 1][1]),
                      pk2(Yacc1[2 * kc + 1][2], Yacc1[2 * kc + 1][3]));
    }
    f32x4 Sacc0 = (f32x4){0.f, 0.f, 0.f, 0.f};
    f32x4 Sacc1 = (f32x4){0.f, 0.f, 0.f, 0.f};
#pragma unroll
    for (int kc = 0; kc < 4; ++kc) {
        Sacc0 = __builtin_amdgcn_mfma_f32_16x16x32_bf16(rpf0[kc], yf0[kc], Sacc0, 0, 0, 0);
        Sacc1 = __builtin_amdgcn_mfma_f32_16x16x32_bf16(rpf1[kc], yf1[kc], Sacc1, 0, 0, 0);
    }

    __syncthreads();  // bar3: lds_gate visible

    // ---- epilogue per column-set ----
    const int jv = c16 & 7;
    const bool diag = ((g >> 1) == np);
    auto do_epi = [&](const f32x4& Sacc, float sjv, float xvv, int s) {
        const int bp = wv * 4 + s * 2 + np;
        const long bt = base + bp;
        float Av[4], pr[4];
#pragma unroll
        for (int q = 0; q < 4; ++q) {
            float sc = (Sacc[q] + sjv + cc) * 0.08838834764831845f;
            float gv = lds_gate[bp][(4 * (g & 1) + q) * 8 + jv];
            Av[q] = fast_tanh(sc) * gv;
            pr[q] = Av[q] * xvv;
            pr[q] += __shfl_xor(pr[q], 1);
            pr[q] += __shfl_xor(pr[q], 2);
            pr[q] += __shfl_xor(pr[q], 4);
        }
        if (diag) {
            float* Ap = A_out + bt * 64 + jv;
#pragma unroll
            for (int q = 0; q < 4; ++q) Ap[((g & 1) * 4 + q) * 8] = Av[q];
            if (jv == 0) {
                float* Pp = pred_out + bt * 8 + (g & 1) * 4;
#pragma unroll
                for (int q = 0; q < 4; ++q) Pp[q] = pr[q];
            }
        }
    };
    do_epi(Sacc0, sj0, xv0, 0);
    do_epi(Sacc1, sj1, xv1, 1);
}

extern "C" void kernel_launch(void* const* d_in, const int* in_sizes, int n_in,
                              void* d_out, int out_size, void* d_ws, size_t ws_size,
                              hipStream_t stream) {
    const float* x = (const float*)d_in[0];
    const float* hist = (const float*)d_in[1];
    const float* ce_w1 = (const float*)d_in[2];
    const float* ce_b1 = (const float*)d_in[3];
    const float* ce_w2 = (const float*)d_in[4];
    const float* ce_b2 = (const float*)d_in[5];
    const float* p_w1 = (const float*)d_in[6];
    const float* p_b1 = (const float*)d_in[7];
    const float* p_w2 = (const float*)d_in[8];
    const float* p_b2 = (const float*)d_in[9];
    const float* wq = (const float*)d_in[10];
    const float* wk = (const float*)d_in[11];

    float* pred_out = (float*)d_out;
    float* A_out = pred_out + (size_t)BTOT * 8;

    k_pre1<<<130, 128, 0, stream>>>(wq, wk, p_w2, p_b2, ce_w1, ce_b1, ce_w2);
    k_pre2<<<33, 128, 0, stream>>>();
    k_fused<<<BTOT / 16, 256, 0, stream>>>(x, hist, ce_b2, p_w1, p_b1, pred_out, A_out);
}